// Round 1
// 768.465 us; speedup vs baseline: 1.2328x; 1.2328x over previous
//
#include <hip/hip_runtime.h>
#include <stdint.h>

#define T_TOK 2048
#define DMODEL 1024
#define FDIM 4096
#define NEXP 8
#define CAP 2048
#define KC2 4   // K-split factor for gemm2 (epilogue is atomic, so K splits freely)

typedef __attribute__((ext_vector_type(8))) short short8;       // 8 bf16 (4 VGPRs)
typedef __attribute__((ext_vector_type(4))) float f32x4;
typedef __attribute__((ext_vector_type(4))) unsigned short us4;
typedef __attribute__((ext_vector_type(8))) unsigned short us8;

__device__ __forceinline__ unsigned short f2bf(float f) {
  union { float f; unsigned int u; } v; v.f = f;
  unsigned int r = (v.u + 0x7fffu + ((v.u >> 16) & 1u)) >> 16;  // RNE
  return (unsigned short)r;
}

// async global->LDS 16B per lane; LDS dest = wave-uniform base + lane*16
__device__ __forceinline__ void async16(const unsigned short* g, unsigned short* l) {
  __builtin_amdgcn_global_load_lds(
      (const __attribute__((address_space(1))) unsigned int*)g,
      (__attribute__((address_space(3))) unsigned int*)l,
      16, 0, 0);
}

// ---------------- gating: logits, softmax, top-2, routing lists ----------------
// 16 tokens per block (4 waves x 4 tokens). All same-address atomics are
// block-reduced in LDS first: global sumprob/top1cnt atomics drop from
// 18,432 to <=2,048 total (128 serialized per address), cnt reservations
// from 4,096 returning-atomics to <=1,024 ranged ones.
__global__ void gate_kernel(const float* __restrict__ x, const float* __restrict__ Wg,
                            const float* __restrict__ bg,
                            int* cnt, int* top1cnt, float* sumprob,
                            int* list, float* wlist) {
  int wave = threadIdx.x >> 6;
  int lane = threadIdx.x & 63;
  __shared__ float sprob[8];
  __shared__ int   stop1[8];
  __shared__ int   ent_e[32];   // 16 tokens x 2 routing entries
  __shared__ float ent_p[32];
  if (threadIdx.x < 8) { sprob[threadIdx.x] = 0.f; stop1[threadIdx.x] = 0; }
  __syncthreads();

#pragma unroll
  for (int i = 0; i < 4; i++) {
    int s = wave * 4 + i;
    int t = blockIdx.x * 16 + s;
    float acc[8];
#pragma unroll
    for (int e = 0; e < 8; e++) acc[e] = 0.f;
    const float* xr = x + (size_t)t * DMODEL;
    for (int c = lane; c < DMODEL / 4; c += 64) {
      f32x4 xv = ((const f32x4*)xr)[c];
      const float* wr = Wg + (size_t)c * 4 * 8;
#pragma unroll
      for (int q = 0; q < 4; q++)
#pragma unroll
        for (int e = 0; e < 8; e++) acc[e] += xv[q] * wr[q * 8 + e];
    }
#pragma unroll
    for (int off = 32; off > 0; off >>= 1) {
#pragma unroll
      for (int e = 0; e < 8; e++) acc[e] += __shfl_down(acc[e], off);
    }
    if (lane == 0) {
      float p[8];
      float m = -1e30f;
#pragma unroll
      for (int e = 0; e < 8; e++) { p[e] = acc[e] + bg[e]; m = fmaxf(m, p[e]); }
      float sum = 0.f;
#pragma unroll
      for (int e = 0; e < 8; e++) { p[e] = __expf(p[e] - m); sum += p[e]; }
      float inv = 1.f / sum;
#pragma unroll
      for (int e = 0; e < 8; e++) p[e] *= inv;
      int e1 = 0; float p1 = p[0];
#pragma unroll
      for (int e = 1; e < 8; e++) if (p[e] > p1) { p1 = p[e]; e1 = e; }   // strict > : lowest idx wins ties
      int e2 = -1; float p2 = -1.f;
#pragma unroll
      for (int e = 0; e < 8; e++) if (e != e1 && p[e] > p2) { p2 = p[e]; e2 = e; }
      atomicAdd(&stop1[e1], 1);                     // LDS atomic
#pragma unroll
      for (int e = 0; e < 8; e++) atomicAdd(&sprob[e], p[e]);   // LDS atomics
      ent_e[2 * s]     = e1; ent_p[2 * s]     = p1;
      ent_e[2 * s + 1] = e2; ent_p[2 * s + 1] = p2;
    }
  }
  __syncthreads();

  if (threadIdx.x < 8) {
    int e = threadIdx.x;
    int n = 0;
#pragma unroll
    for (int j = 0; j < 32; j++) n += (ent_e[j] == e) ? 1 : 0;
    if (n) {
      int pos = atomicAdd(cnt + e, n);              // one ranged reservation per expert per block
#pragma unroll
      for (int j = 0; j < 32; j++) {
        if (ent_e[j] == e) {
          list[e * CAP + pos]  = blockIdx.x * 16 + (j >> 1);
          wlist[e * CAP + pos] = ent_p[j];
          pos++;
        }
      }
    }
    atomicAdd(sumprob + e, sprob[e]);               // one per expert per block
    int c = stop1[e];
    if (c) atomicAdd(top1cnt + e, c);
  }
}

// ---------------- offsets (prefix sum) + aux loss ----------------
__global__ void offs_aux_kernel(const int* cnt, const int* top1cnt, const float* sumprob,
                                int* offs, float* out_aux) {
  if (threadIdx.x == 0 && blockIdx.x == 0) {
    int off = 0;
    float aux = 0.f;
    for (int e = 0; e < 8; e++) {
      offs[e] = off; off += cnt[e];
      aux += ((float)top1cnt[e] / ((float)T_TOK + 1e-8f)) * (sumprob[e] / (float)T_TOK);
    }
    *out_aux = aux * (float)NEXP;
  }
}

// ---------------- gather x rows into compact bf16 buffer ----------------
__global__ void gather_kernel(const float* __restrict__ x, const int* __restrict__ list,
                              const int* __restrict__ cnt, const int* __restrict__ offs,
                              unsigned short* __restrict__ xg) {
  int e = blockIdx.x >> 11;
  int i = blockIdx.x & 2047;
  if (i >= cnt[e]) return;
  int t = list[e * CAP + i];
  int row = offs[e] + i;
  const f32x4* src = (const f32x4*)(x + (size_t)t * DMODEL);
  us4* dst = (us4*)(xg + (size_t)row * DMODEL);
  int j = threadIdx.x;                 // 256 threads x 4 elems = 1024
  f32x4 v = src[j];
  us4 o; o.x = f2bf(v.x); o.y = f2bf(v.y); o.z = f2bf(v.z); o.w = f2bf(v.w);
  dst[j] = o;
}

// ---- convert+transpose slice: fp32 [E][K][Nfull] cols [n_off,n_off+NS) -> bf16 [E][NS][K] ----
__launch_bounds__(256)
__global__ void convt_kernel(const float* __restrict__ in, unsigned short* __restrict__ out,
                             int K, int Nfull, int NS, int n_off) {
  int e = blockIdx.y;
  int ntn = NS >> 6;
  int tk = blockIdx.x / ntn, tn = blockIdx.x % ntn;
  const float* src = in + (size_t)e * K * Nfull + (size_t)(tk * 64) * Nfull + n_off + tn * 64;
  unsigned short* dst = out + (size_t)e * NS * K + (size_t)(tn * 64) * K + tk * 64;
  __shared__ unsigned short Ls[64 * 72];
  int t = threadIdx.x;
  int k = t >> 4, n4 = (t & 15) * 4;
#pragma unroll
  for (int i = 0; i < 4; i++) {
    int kk = k + 16 * i;
    f32x4 v = *(const f32x4*)&src[(size_t)kk * Nfull + n4];
    Ls[(n4 + 0) * 72 + kk] = f2bf(v.x);
    Ls[(n4 + 1) * 72 + kk] = f2bf(v.y);
    Ls[(n4 + 2) * 72 + kk] = f2bf(v.z);
    Ls[(n4 + 3) * 72 + kk] = f2bf(v.w);
  }
  __syncthreads();
  int n = t >> 3, k8 = (t & 7) * 8;
#pragma unroll
  for (int j = 0; j < 2; j++) {
    int nn = n + 32 * j;
    us8 v = *(const us8*)&Ls[nn * 72 + k8];
    *(us8*)&dst[(size_t)nn * K + k8] = v;
  }
}

// ---------------- GEMM1 slice: h[:, n_off:n_off+NS] = relu(xg @ W1slice + b1) ----------------
__launch_bounds__(256)
__global__ void gemm1_kernel(const unsigned short* __restrict__ xg,
                             const unsigned short* __restrict__ Wt,   // [E][NS][D] bf16
                             const float* __restrict__ b1,
                             const int* __restrict__ cnt, const int* __restrict__ offs,
                             unsigned short* __restrict__ h, int NS, int n_off) {
  int e = blockIdx.x >> 4;
  int mt = blockIdx.x & 15;
  int count = cnt[e];
  if (mt * 128 >= count) return;
  int nloc = blockIdx.y * 128;
  int base = offs[e];
  const unsigned short* A = xg + (size_t)(base + mt * 128) * DMODEL;
  const unsigned short* B = Wt + (size_t)e * NS * DMODEL + (size_t)nloc * DMODEL;

  __shared__ unsigned short As[128 * 32];
  __shared__ unsigned short Bs[128 * 32];

  int tid = threadIdx.x;
  int w = tid >> 6, lane = tid & 63;
  int wr = w >> 1, wc = w & 1;
  int l16 = lane & 15, quad = lane >> 4;
  int lrow = lane >> 2, lseg = lane & 3;

  f32x4 acc[4][4];
#pragma unroll
  for (int i = 0; i < 4; i++)
#pragma unroll
    for (int j = 0; j < 4; j++)
#pragma unroll
      for (int r = 0; r < 4; r++) acc[i][j][r] = 0.f;

  const unsigned short* Ab = A + (size_t)(w * 32 + lrow) * DMODEL + lseg * 8;
  const unsigned short* Bb = B + (size_t)(w * 32 + lrow) * DMODEL + lseg * 8;
  unsigned short* Ad0 = &As[(w * 32) * 32];
  unsigned short* Ad1 = &As[(w * 32 + 16) * 32];
  unsigned short* Bd0 = &Bs[(w * 32) * 32];
  unsigned short* Bd1 = &Bs[(w * 32 + 16) * 32];

  for (int kb = 0; kb < DMODEL / 32; kb++) {
    int ko = kb * 32;
    async16(Ab + ko, Ad0);
    async16(Ab + ko + 16 * DMODEL, Ad1);
    async16(Bb + ko, Bd0);
    async16(Bb + ko + 16 * DMODEL, Bd1);
    __syncthreads();
    short8 af[4], bf[4];
#pragma unroll
    for (int i = 0; i < 4; i++)
      af[i] = *(const short8*)&As[(wr * 64 + i * 16 + l16) * 32 + quad * 8];
#pragma unroll
    for (int j = 0; j < 4; j++)
      bf[j] = *(const short8*)&Bs[(wc * 64 + j * 16 + l16) * 32 + quad * 8];
#pragma unroll
    for (int i = 0; i < 4; i++)
#pragma unroll
      for (int j = 0; j < 4; j++)
        acc[i][j] = __builtin_amdgcn_mfma_f32_16x16x32_bf16(af[i], bf[j], acc[i][j], 0, 0, 0);
    __syncthreads();
  }

  // guard row<count: packed expert rows — unguarded writes clobber next expert (round-2 bug)
#pragma unroll
  for (int j = 0; j < 4; j++) {
    int ncol = n_off + nloc + wc * 64 + j * 16 + l16;
    float bias = b1[e * FDIM + ncol];
#pragma unroll
    for (int i = 0; i < 4; i++) {
      int rbase = mt * 128 + wr * 64 + i * 16 + quad * 4;
#pragma unroll
      for (int r = 0; r < 4; r++) {
        int row = rbase + r;
        if (row < count) {
          float v = fmaxf(acc[i][j][r] + bias, 0.f);
          h[(size_t)(base + row) * FDIM + ncol] = f2bf(v);
        }
      }
    }
  }
}

// ---------------- GEMM2 slice: out[tok, n] += w * (h @ W2slice + b2) ----------------
// K (=FDIM) split across blockIdx.z in KC2 chunks; bias added only by chunk 0.
// Epilogue was already atomic, so K-splitting is free and lifts active-block
// count from ~36 to ~144 per slice.
__launch_bounds__(256)
__global__ void gemm2_kernel(const unsigned short* __restrict__ h,
                             const unsigned short* __restrict__ Wt,   // [E][NS][F] bf16
                             const float* __restrict__ b2,
                             const int* __restrict__ cnt, const int* __restrict__ offs,
                             const int* __restrict__ list, const float* __restrict__ wlist,
                             float* __restrict__ out, int NS, int n_off) {
  int e = blockIdx.x >> 4;
  int mt = blockIdx.x & 15;
  int count = cnt[e];
  if (mt * 128 >= count) return;
  int nloc = blockIdx.y * 128;
  int kc = blockIdx.z;
  int base = offs[e];
  const unsigned short* A = h + (size_t)(base + mt * 128) * FDIM;
  const unsigned short* B = Wt + (size_t)e * NS * FDIM + (size_t)nloc * FDIM;

  __shared__ unsigned short As[128 * 32];
  __shared__ unsigned short Bs[128 * 32];

  int tid = threadIdx.x;
  int w = tid >> 6, lane = tid & 63;
  int wr = w >> 1, wc = w & 1;
  int l16 = lane & 15, quad = lane >> 4;
  int lrow = lane >> 2, lseg = lane & 3;

  f32x4 acc[4][4];
#pragma unroll
  for (int i = 0; i < 4; i++)
#pragma unroll
    for (int j = 0; j < 4; j++)
#pragma unroll
      for (int r = 0; r < 4; r++) acc[i][j][r] = 0.f;

  const unsigned short* Ab = A + (size_t)(w * 32 + lrow) * FDIM + lseg * 8;
  const unsigned short* Bb = B + (size_t)(w * 32 + lrow) * FDIM + lseg * 8;
  unsigned short* Ad0 = &As[(w * 32) * 32];
  unsigned short* Ad1 = &As[(w * 32 + 16) * 32];
  unsigned short* Bd0 = &Bs[(w * 32) * 32];
  unsigned short* Bd1 = &Bs[(w * 32 + 16) * 32];

  const int KB_PER = FDIM / KC2 / 32;
  for (int kb = kc * KB_PER; kb < (kc + 1) * KB_PER; kb++) {
    int ko = kb * 32;
    async16(Ab + ko, Ad0);
    async16(Ab + ko + 16 * FDIM, Ad1);
    async16(Bb + ko, Bd0);
    async16(Bb + ko + 16 * FDIM, Bd1);
    __syncthreads();
    short8 af[4], bf[4];
#pragma unroll
    for (int i = 0; i < 4; i++)
      af[i] = *(const short8*)&As[(wr * 64 + i * 16 + l16) * 32 + quad * 8];
#pragma unroll
    for (int j = 0; j < 4; j++)
      bf[j] = *(const short8*)&Bs[(wc * 64 + j * 16 + l16) * 32 + quad * 8];
#pragma unroll
    for (int i = 0; i < 4; i++)
#pragma unroll
      for (int j = 0; j < 4; j++)
        acc[i][j] = __builtin_amdgcn_mfma_f32_16x16x32_bf16(af[i], bf[j], acc[i][j], 0, 0, 0);
    __syncthreads();
  }

  float bv[4];
#pragma unroll
  for (int j = 0; j < 4; j++)
    bv[j] = (kc == 0) ? b2[e * DMODEL + n_off + nloc + wc * 64 + j * 16 + l16] : 0.f;

#pragma unroll
  for (int i = 0; i < 4; i++) {
    int rbase = mt * 128 + wr * 64 + i * 16 + quad * 4;
#pragma unroll
    for (int r = 0; r < 4; r++) {
      int row = rbase + r;
      if (row >= count) continue;
      int tok = list[e * CAP + row];
      float wgt = wlist[e * CAP + row];
#pragma unroll
      for (int j = 0; j < 4; j++) {
        int ncol = n_off + nloc + wc * 64 + j * 16 + l16;
        atomicAdd(out + (size_t)tok * DMODEL + ncol, wgt * (acc[i][j][r] + bv[j]));
      }
    }
  }
}

extern "C" void kernel_launch(void* const* d_in, const int* in_sizes, int n_in,
                              void* d_out, int out_size, void* d_ws, size_t ws_size,
                              hipStream_t stream) {
  const float* x  = (const float*)d_in[0];
  const float* Wg = (const float*)d_in[1];
  const float* bg = (const float*)d_in[2];
  const float* W1 = (const float*)d_in[3];
  const float* b1 = (const float*)d_in[4];
  const float* W2 = (const float*)d_in[5];
  const float* b2 = (const float*)d_in[6];
  float* out = (float*)d_out;

  // Tight layout — ws usage proven safe up to 51.38 MB (round 1 passed full
  // timing at 51.38 MB). Buffer read-overruns from GEMM tile padding spill
  // into the NEXT buffer; those values feed only guarded-out accumulators.
  char* ws = (char*)d_ws;
  int*   cnt     = (int*)(ws + 0);
  int*   top1cnt = (int*)(ws + 32);
  int*   offs    = (int*)(ws + 64);
  float* sumprob = (float*)(ws + 96);
  int*   list    = (int*)(ws + 4096);                         // 64 KB
  float* wlist   = (float*)(ws + 4096 + 65536);               // 64 KB -> ends 135,168
  unsigned short* xg = (unsigned short*)(ws + 135168);        // 4096x1024 bf16 = 8,388,608 -> ends 8,523,776
  unsigned short* h  = (unsigned short*)(ws + 8523776);       // 4096x4096 bf16 = 33,554,432 -> ends 42,078,208
  unsigned short* Wt = (unsigned short*)(ws + 42078208);      // weight slice, 67,108,864/S bytes

  // pick slice count S from ws_size (stable across calls -> same work every call)
  const size_t baseBytes = 42078208ull;
  int S;
  if      (ws_size >= baseBytes + 67108864ull) S = 1;
  else if (ws_size >= baseBytes + 33554432ull) S = 2;
  else if (ws_size >= baseBytes + 16777216ull) S = 4;
  else                                         S = 8;   // needs 50.47 MB <= proven 51.38 MB

  hipMemsetAsync(ws, 0, 1024, stream);
  hipMemsetAsync(d_out, 0, (size_t)out_size * sizeof(float), stream);

  gate_kernel<<<T_TOK / 16, 256, 0, stream>>>(x, Wg, bg, cnt, top1cnt, sumprob, list, wlist);
  offs_aux_kernel<<<1, 64, 0, stream>>>(cnt, top1cnt, sumprob, offs, out + (size_t)T_TOK * DMODEL);
  gather_kernel<<<NEXP * CAP, 256, 0, stream>>>(x, list, cnt, offs, xg);

  int NS1 = FDIM / S;
  for (int s = 0; s < S; s++) {
    convt_kernel<<<dim3((DMODEL / 64) * (NS1 / 64), NEXP), 256, 0, stream>>>(
        W1, Wt, DMODEL, FDIM, NS1, s * NS1);
    gemm1_kernel<<<dim3(NEXP * 16, NS1 / 128), 256, 0, stream>>>(
        xg, Wt, b1, cnt, offs, h, NS1, s * NS1);
  }
  int NS2 = DMODEL / S;
  for (int s = 0; s < S; s++) {
    convt_kernel<<<dim3((FDIM / 64) * (NS2 / 64), NEXP), 256, 0, stream>>>(
        W2, Wt, FDIM, DMODEL, NS2, s * NS2);
    gemm2_kernel<<<dim3(NEXP * 16, NS2 / 128, KC2), 256, 0, stream>>>(
        h, Wt, b2, cnt, offs, list, wlist, out, NS2, s * NS2);
  }
}

// Round 2
// 749.770 us; speedup vs baseline: 1.2635x; 1.0249x over previous
//
#include <hip/hip_runtime.h>
#include <stdint.h>

#define T_TOK 2048
#define DMODEL 1024
#define FDIM 4096
#define NEXP 8
#define CAP 2048

typedef __attribute__((ext_vector_type(8))) short short8;       // 8 bf16 (4 VGPRs)
typedef __attribute__((ext_vector_type(4))) float f32x4;
typedef __attribute__((ext_vector_type(4))) unsigned short us4;
typedef __attribute__((ext_vector_type(8))) unsigned short us8;

__device__ __forceinline__ unsigned short f2bf(float f) {
  union { float f; unsigned int u; } v; v.f = f;
  unsigned int r = (v.u + 0x7fffu + ((v.u >> 16) & 1u)) >> 16;  // RNE
  return (unsigned short)r;
}

// async global->LDS 16B per lane; LDS dest = wave-uniform base + lane*16
__device__ __forceinline__ void async16(const unsigned short* g, unsigned short* l) {
  __builtin_amdgcn_global_load_lds(
      (const __attribute__((address_space(1))) unsigned int*)g,
      (__attribute__((address_space(3))) unsigned int*)l,
      16, 0, 0);
}

// ---------------- gating: logits, softmax, top-2, routing lists ----------------
// 16 tokens per block; LDS-aggregated atomics. Also records, per token, its
// (expert,pos) slot pair so the combine kernel can gather without scatter-adds.
__global__ void gate_kernel(const float* __restrict__ x, const float* __restrict__ Wg,
                            const float* __restrict__ bg,
                            int* cnt, int* top1cnt, float* sumprob,
                            int* list, float* wlist, int* tok2slot) {
  int wave = threadIdx.x >> 6;
  int lane = threadIdx.x & 63;
  __shared__ float sprob[8];
  __shared__ int   stop1[8];
  __shared__ int   ent_e[32];   // 16 tokens x 2 routing entries
  __shared__ float ent_p[32];
  if (threadIdx.x < 8) { sprob[threadIdx.x] = 0.f; stop1[threadIdx.x] = 0; }
  __syncthreads();

#pragma unroll
  for (int i = 0; i < 4; i++) {
    int s = wave * 4 + i;
    int t = blockIdx.x * 16 + s;
    float acc[8];
#pragma unroll
    for (int e = 0; e < 8; e++) acc[e] = 0.f;
    const float* xr = x + (size_t)t * DMODEL;
    for (int c = lane; c < DMODEL / 4; c += 64) {
      f32x4 xv = ((const f32x4*)xr)[c];
      const float* wr = Wg + (size_t)c * 4 * 8;
#pragma unroll
      for (int q = 0; q < 4; q++)
#pragma unroll
        for (int e = 0; e < 8; e++) acc[e] += xv[q] * wr[q * 8 + e];
    }
#pragma unroll
    for (int off = 32; off > 0; off >>= 1) {
#pragma unroll
      for (int e = 0; e < 8; e++) acc[e] += __shfl_down(acc[e], off);
    }
    if (lane == 0) {
      float p[8];
      float m = -1e30f;
#pragma unroll
      for (int e = 0; e < 8; e++) { p[e] = acc[e] + bg[e]; m = fmaxf(m, p[e]); }
      float sum = 0.f;
#pragma unroll
      for (int e = 0; e < 8; e++) { p[e] = __expf(p[e] - m); sum += p[e]; }
      float inv = 1.f / sum;
#pragma unroll
      for (int e = 0; e < 8; e++) p[e] *= inv;
      int e1 = 0; float p1 = p[0];
#pragma unroll
      for (int e = 1; e < 8; e++) if (p[e] > p1) { p1 = p[e]; e1 = e; }   // strict > : lowest idx wins ties
      int e2 = -1; float p2 = -1.f;
#pragma unroll
      for (int e = 0; e < 8; e++) if (e != e1 && p[e] > p2) { p2 = p[e]; e2 = e; }
      atomicAdd(&stop1[e1], 1);                     // LDS atomic
#pragma unroll
      for (int e = 0; e < 8; e++) atomicAdd(&sprob[e], p[e]);   // LDS atomics
      ent_e[2 * s]     = e1; ent_p[2 * s]     = p1;
      ent_e[2 * s + 1] = e2; ent_p[2 * s + 1] = p2;
    }
  }
  __syncthreads();

  if (threadIdx.x < 8) {
    int e = threadIdx.x;
    int n = 0;
#pragma unroll
    for (int j = 0; j < 32; j++) n += (ent_e[j] == e) ? 1 : 0;
    if (n) {
      int pos = atomicAdd(cnt + e, n);              // one ranged reservation per expert per block
#pragma unroll
      for (int j = 0; j < 32; j++) {
        if (ent_e[j] == e) {
          int t = blockIdx.x * 16 + (j >> 1);
          list[e * CAP + pos]  = t;
          wlist[e * CAP + pos] = ent_p[j];
          tok2slot[2 * t + (j & 1)] = (e << 16) | pos;   // pos < 2048 fits 16 bits
          pos++;
        }
      }
    }
    atomicAdd(sumprob + e, sprob[e]);               // one per expert per block
    int c = stop1[e];
    if (c) atomicAdd(top1cnt + e, c);
  }
}

// ---------------- offsets (prefix sum) + aux loss ----------------
__global__ void offs_aux_kernel(const int* cnt, const int* top1cnt, const float* sumprob,
                                int* offs, float* out_aux) {
  if (threadIdx.x == 0 && blockIdx.x == 0) {
    int off = 0;
    float aux = 0.f;
    for (int e = 0; e < 8; e++) {
      offs[e] = off; off += cnt[e];
      aux += ((float)top1cnt[e] / ((float)T_TOK + 1e-8f)) * (sumprob[e] / (float)T_TOK);
    }
    *out_aux = aux * (float)NEXP;
  }
}

// ---------------- gather x rows into compact bf16 buffer ----------------
__global__ void gather_kernel(const float* __restrict__ x, const int* __restrict__ list,
                              const int* __restrict__ cnt, const int* __restrict__ offs,
                              unsigned short* __restrict__ xg) {
  int e = blockIdx.x >> 11;
  int i = blockIdx.x & 2047;
  if (i >= cnt[e]) return;
  int t = list[e * CAP + i];
  int row = offs[e] + i;
  const f32x4* src = (const f32x4*)(x + (size_t)t * DMODEL);
  us4* dst = (us4*)(xg + (size_t)row * DMODEL);
  int j = threadIdx.x;                 // 256 threads x 4 elems = 1024
  f32x4 v = src[j];
  us4 o; o.x = f2bf(v.x); o.y = f2bf(v.y); o.z = f2bf(v.z); o.w = f2bf(v.w);
  dst[j] = o;
}

// ---- convert+transpose: fp32 in[E][Kfull][Nfull], k-slice [k_off,k_off+KS) and
// n-slice [n_off,n_off+NS) -> bf16 out[E][NS][KS] (row = n, contiguous = k) ----
__launch_bounds__(256)
__global__ void convt_kernel(const float* __restrict__ in, unsigned short* __restrict__ out,
                             int Kfull, int Nfull, int KS, int k_off, int NS, int n_off) {
  int e = blockIdx.y;
  int ntn = NS >> 6;
  int tk = blockIdx.x / ntn, tn = blockIdx.x % ntn;
  const float* src = in + (size_t)e * Kfull * Nfull + (size_t)(k_off + tk * 64) * Nfull + n_off + tn * 64;
  unsigned short* dst = out + (size_t)e * NS * KS + (size_t)(tn * 64) * KS + tk * 64;
  __shared__ unsigned short Ls[64 * 72];
  int t = threadIdx.x;
  int k = t >> 4, n4 = (t & 15) * 4;
#pragma unroll
  for (int i = 0; i < 4; i++) {
    int kk = k + 16 * i;
    f32x4 v = *(const f32x4*)&src[(size_t)kk * Nfull + n4];
    Ls[(n4 + 0) * 72 + kk] = f2bf(v.x);
    Ls[(n4 + 1) * 72 + kk] = f2bf(v.y);
    Ls[(n4 + 2) * 72 + kk] = f2bf(v.z);
    Ls[(n4 + 3) * 72 + kk] = f2bf(v.w);
  }
  __syncthreads();
  int n = t >> 3, k8 = (t & 7) * 8;
#pragma unroll
  for (int j = 0; j < 2; j++) {
    int nn = n + 32 * j;
    us8 v = *(const us8*)&Ls[nn * 72 + k8];
    *(us8*)&dst[(size_t)nn * KS + k8] = v;
  }
}

// ---------------- GEMM1 slice: h_s[:, 0:NS] = relu(xg @ W1[:, n_off:n_off+NS] + b1) ----------------
__launch_bounds__(256)
__global__ void gemm1_kernel(const unsigned short* __restrict__ xg,
                             const unsigned short* __restrict__ Wt,   // [E][NS][D] bf16
                             const float* __restrict__ b1,
                             const int* __restrict__ cnt, const int* __restrict__ offs,
                             unsigned short* __restrict__ h, int NS, int n_off) {
  int e = blockIdx.x >> 4;
  int mt = blockIdx.x & 15;
  int count = cnt[e];
  if (mt * 128 >= count) return;
  int nloc = blockIdx.y * 128;
  int base = offs[e];
  const unsigned short* A = xg + (size_t)(base + mt * 128) * DMODEL;
  const unsigned short* B = Wt + (size_t)e * NS * DMODEL + (size_t)nloc * DMODEL;

  __shared__ unsigned short As[128 * 32];
  __shared__ unsigned short Bs[128 * 32];

  int tid = threadIdx.x;
  int w = tid >> 6, lane = tid & 63;
  int wr = w >> 1, wc = w & 1;
  int l16 = lane & 15, quad = lane >> 4;
  int lrow = lane >> 2, lseg = lane & 3;

  f32x4 acc[4][4];
#pragma unroll
  for (int i = 0; i < 4; i++)
#pragma unroll
    for (int j = 0; j < 4; j++)
#pragma unroll
      for (int r = 0; r < 4; r++) acc[i][j][r] = 0.f;

  const unsigned short* Ab = A + (size_t)(w * 32 + lrow) * DMODEL + lseg * 8;
  const unsigned short* Bb = B + (size_t)(w * 32 + lrow) * DMODEL + lseg * 8;
  unsigned short* Ad0 = &As[(w * 32) * 32];
  unsigned short* Ad1 = &As[(w * 32 + 16) * 32];
  unsigned short* Bd0 = &Bs[(w * 32) * 32];
  unsigned short* Bd1 = &Bs[(w * 32 + 16) * 32];

  for (int kb = 0; kb < DMODEL / 32; kb++) {
    int ko = kb * 32;
    async16(Ab + ko, Ad0);
    async16(Ab + ko + 16 * DMODEL, Ad1);
    async16(Bb + ko, Bd0);
    async16(Bb + ko + 16 * DMODEL, Bd1);
    __syncthreads();
    short8 af[4], bf[4];
#pragma unroll
    for (int i = 0; i < 4; i++)
      af[i] = *(const short8*)&As[(wr * 64 + i * 16 + l16) * 32 + quad * 8];
#pragma unroll
    for (int j = 0; j < 4; j++)
      bf[j] = *(const short8*)&Bs[(wc * 64 + j * 16 + l16) * 32 + quad * 8];
#pragma unroll
    for (int i = 0; i < 4; i++)
#pragma unroll
      for (int j = 0; j < 4; j++)
        acc[i][j] = __builtin_amdgcn_mfma_f32_16x16x32_bf16(af[i], bf[j], acc[i][j], 0, 0, 0);
    __syncthreads();
  }

  // guard row<count: packed expert rows — unguarded writes clobber next expert
#pragma unroll
  for (int j = 0; j < 4; j++) {
    int ncl = nloc + wc * 64 + j * 16 + l16;           // local col within slice
    float bias = b1[e * FDIM + n_off + ncl];
#pragma unroll
    for (int i = 0; i < 4; i++) {
      int rbase = mt * 128 + wr * 64 + i * 16 + quad * 4;
#pragma unroll
      for (int r = 0; r < 4; r++) {
        int row = rbase + r;
        if (row < count) {
          float v = fmaxf(acc[i][j][r] + bias, 0.f);
          h[(size_t)(base + row) * NS + ncl] = f2bf(v);
        }
      }
    }
  }
}

// ---------------- GEMM2 slice: y[row, :] (+)= h_s @ W2[f_slice, :] (+ b2 on first slice) ----
// Dense per-routed-row output, plain stores / read-add-store. NO atomics.
__launch_bounds__(256)
__global__ void gemm2_kernel(const unsigned short* __restrict__ h,
                             const unsigned short* __restrict__ Wt,   // [E][D][KS] bf16
                             const float* __restrict__ b2,
                             const int* __restrict__ cnt, const int* __restrict__ offs,
                             float* __restrict__ y, int KS, int first) {
  int e = blockIdx.x >> 4;
  int mt = blockIdx.x & 15;
  int count = cnt[e];
  if (mt * 128 >= count) return;
  int nloc = blockIdx.y * 128;
  int base = offs[e];
  const unsigned short* A = h + (size_t)(base + mt * 128) * KS;
  const unsigned short* B = Wt + (size_t)e * DMODEL * KS + (size_t)nloc * KS;

  __shared__ unsigned short As[128 * 32];
  __shared__ unsigned short Bs[128 * 32];

  int tid = threadIdx.x;
  int w = tid >> 6, lane = tid & 63;
  int wr = w >> 1, wc = w & 1;
  int l16 = lane & 15, quad = lane >> 4;
  int lrow = lane >> 2, lseg = lane & 3;

  f32x4 acc[4][4];
#pragma unroll
  for (int i = 0; i < 4; i++)
#pragma unroll
    for (int j = 0; j < 4; j++)
#pragma unroll
      for (int r = 0; r < 4; r++) acc[i][j][r] = 0.f;

  const unsigned short* Ab = A + (size_t)(w * 32 + lrow) * KS + lseg * 8;
  const unsigned short* Bb = B + (size_t)(w * 32 + lrow) * KS + lseg * 8;
  unsigned short* Ad0 = &As[(w * 32) * 32];
  unsigned short* Ad1 = &As[(w * 32 + 16) * 32];
  unsigned short* Bd0 = &Bs[(w * 32) * 32];
  unsigned short* Bd1 = &Bs[(w * 32 + 16) * 32];

  for (int kb = 0; kb < KS / 32; kb++) {
    int ko = kb * 32;
    async16(Ab + ko, Ad0);
    async16(Ab + ko + 16 * KS, Ad1);
    async16(Bb + ko, Bd0);
    async16(Bb + ko + 16 * KS, Bd1);
    __syncthreads();
    short8 af[4], bf[4];
#pragma unroll
    for (int i = 0; i < 4; i++)
      af[i] = *(const short8*)&As[(wr * 64 + i * 16 + l16) * 32 + quad * 8];
#pragma unroll
    for (int j = 0; j < 4; j++)
      bf[j] = *(const short8*)&Bs[(wc * 64 + j * 16 + l16) * 32 + quad * 8];
#pragma unroll
    for (int i = 0; i < 4; i++)
#pragma unroll
      for (int j = 0; j < 4; j++)
        acc[i][j] = __builtin_amdgcn_mfma_f32_16x16x32_bf16(af[i], bf[j], acc[i][j], 0, 0, 0);
    __syncthreads();
  }

  float bv[4];
#pragma unroll
  for (int j = 0; j < 4; j++)
    bv[j] = first ? b2[e * DMODEL + nloc + wc * 64 + j * 16 + l16] : 0.f;

#pragma unroll
  for (int i = 0; i < 4; i++) {
    int rbase = mt * 128 + wr * 64 + i * 16 + quad * 4;
#pragma unroll
    for (int r = 0; r < 4; r++) {
      int row = rbase + r;
      if (row >= count) continue;       // packed rows: unguarded writes clobber next expert
      float* yr = y + (size_t)(base + row) * DMODEL;
#pragma unroll
      for (int j = 0; j < 4; j++) {
        int ncol = nloc + wc * 64 + j * 16 + l16;
        float v = acc[i][j][r] + bv[j];
        if (first) yr[ncol] = v;
        else       yr[ncol] += v;
      }
    }
  }
}

// ---------------- combine: out[t,:] = w0*y[r0,:] + w1*y[r1,:] ----------------
__global__ void combine_kernel(const float* __restrict__ y, const int* __restrict__ offs,
                               const int* __restrict__ tok2slot, const float* __restrict__ wlist,
                               float* __restrict__ out) {
  int t = blockIdx.x;
  int s0 = tok2slot[2 * t], s1 = tok2slot[2 * t + 1];
  int e0 = s0 >> 16, p0 = s0 & 0xffff;
  int e1 = s1 >> 16, p1 = s1 & 0xffff;
  float w0 = wlist[e0 * CAP + p0], w1 = wlist[e1 * CAP + p1];
  int r0 = offs[e0] + p0, r1 = offs[e1] + p1;
  int j = threadIdx.x * 4;
  f32x4 a = *(const f32x4*)&y[(size_t)r0 * DMODEL + j];
  f32x4 b = *(const f32x4*)&y[(size_t)r1 * DMODEL + j];
  f32x4 o;
  o.x = w0 * a.x + w1 * b.x;
  o.y = w0 * a.y + w1 * b.y;
  o.z = w0 * a.z + w1 * b.z;
  o.w = w0 * a.w + w1 * b.w;
  *(f32x4*)&out[(size_t)t * DMODEL + j] = o;
}

extern "C" void kernel_launch(void* const* d_in, const int* in_sizes, int n_in,
                              void* d_out, int out_size, void* d_ws, size_t ws_size,
                              hipStream_t stream) {
  const float* x  = (const float*)d_in[0];
  const float* Wg = (const float*)d_in[1];
  const float* bg = (const float*)d_in[2];
  const float* W1 = (const float*)d_in[3];
  const float* b1 = (const float*)d_in[4];
  const float* W2 = (const float*)d_in[5];
  const float* b2 = (const float*)d_in[6];
  float* out = (float*)d_out;

  // Workspace layout (S=4 total: 50,483,200 B <= proven-safe 51.38 MB):
  //   small @0..128 | list 64K @4096 | wlist 64K @69632 | tok2slot 16K @135168
  //   xg 8M @151552 | h_s 32M/S | y 16M | Wt 64M/S
  char* ws = (char*)d_ws;
  int*   cnt      = (int*)(ws + 0);
  int*   top1cnt  = (int*)(ws + 32);
  int*   offs     = (int*)(ws + 64);
  float* sumprob  = (float*)(ws + 96);
  int*   list     = (int*)(ws + 4096);
  float* wlist    = (float*)(ws + 69632);
  int*   tok2slot = (int*)(ws + 135168);
  unsigned short* xg = (unsigned short*)(ws + 151552);        // 8,388,608 B -> 8,540,160

  // pick slice count S from ws_size (stable across calls -> same work every call)
  const size_t fixed = 8540160ull + 16777216ull;              // ..xg end + y
  int S = 8;
  if      (ws_size >= fixed + 100663296ull)     S = 1;
  else if (ws_size >= fixed + 100663296ull / 2) S = 2;
  else if (ws_size >= fixed + 100663296ull / 4) S = 4;        // 50.48 MB
  const int NS1 = FDIM / S;
  unsigned short* h  = (unsigned short*)(ws + 8540160);                        // 33,554,432/S
  float*          y  = (float*)(ws + 8540160 + 33554432ull / S);               // 16 MB
  unsigned short* Wt = (unsigned short*)(ws + 8540160 + 33554432ull / S + 16777216ull);

  hipMemsetAsync(ws, 0, 1024, stream);

  gate_kernel<<<T_TOK / 16, 256, 0, stream>>>(x, Wg, bg, cnt, top1cnt, sumprob, list, wlist, tok2slot);
  offs_aux_kernel<<<1, 64, 0, stream>>>(cnt, top1cnt, sumprob, offs, out + (size_t)T_TOK * DMODEL);
  gather_kernel<<<NEXP * CAP, 256, 0, stream>>>(x, list, cnt, offs, xg);

  for (int s = 0; s < S; s++) {
    // W1 slice: in [E][D][F], k=d full, n=f slice -> Wt [E][NS1][D]
    convt_kernel<<<dim3((DMODEL / 64) * (NS1 / 64), NEXP), 256, 0, stream>>>(
        W1, Wt, DMODEL, FDIM, DMODEL, 0, NS1, s * NS1);
    gemm1_kernel<<<dim3(NEXP * 16, NS1 / 128), 256, 0, stream>>>(
        xg, Wt, b1, cnt, offs, h, NS1, s * NS1);
    // W2 slice: in [E][F][D], k=f slice, n=d full -> Wt [E][D][NS1]
    convt_kernel<<<dim3((NS1 / 64) * (DMODEL / 64), NEXP), 256, 0, stream>>>(
        W2, Wt, FDIM, DMODEL, NS1, s * NS1, DMODEL, 0);
    gemm2_kernel<<<dim3(NEXP * 16, DMODEL / 128), 256, 0, stream>>>(
        h, Wt, b2, cnt, offs, y, NS1, s == 0 ? 1 : 0);
  }

  combine_kernel<<<T_TOK, 256, 0, stream>>>(y, offs, tok2slot, wlist, out);
}

// Round 3
// 591.378 us; speedup vs baseline: 1.6019x; 1.2678x over previous
//
#include <hip/hip_runtime.h>
#include <stdint.h>

#define T_TOK 2048
#define DMODEL 1024
#define FDIM 4096
#define NEXP 8
#define CAP 2048

typedef __attribute__((ext_vector_type(8))) short short8;       // 8 bf16 (4 VGPRs)
typedef __attribute__((ext_vector_type(4))) float f32x4;
typedef __attribute__((ext_vector_type(4))) unsigned short us4;
typedef __attribute__((ext_vector_type(8))) unsigned short us8;

__device__ __forceinline__ unsigned short f2bf(float f) {
  union { float f; unsigned int u; } v; v.f = f;
  unsigned int r = (v.u + 0x7fffu + ((v.u >> 16) & 1u)) >> 16;  // RNE
  return (unsigned short)r;
}

// async global->LDS 16B per lane; LDS dest = wave-uniform base + lane*16
__device__ __forceinline__ void async16(const unsigned short* g, unsigned short* l) {
  __builtin_amdgcn_global_load_lds(
      (const __attribute__((address_space(1))) unsigned int*)g,
      (__attribute__((address_space(3))) unsigned int*)l,
      16, 0, 0);
}

// ---------------- gating: logits, softmax, top-2, routing lists ----------------
__global__ void gate_kernel(const float* __restrict__ x, const float* __restrict__ Wg,
                            const float* __restrict__ bg,
                            int* cnt, int* top1cnt, float* sumprob,
                            int* list, float* wlist, int* tok2slot) {
  int wave = threadIdx.x >> 6;
  int lane = threadIdx.x & 63;
  __shared__ float sprob[8];
  __shared__ int   stop1[8];
  __shared__ int   ent_e[32];   // 16 tokens x 2 routing entries
  __shared__ float ent_p[32];
  if (threadIdx.x < 8) { sprob[threadIdx.x] = 0.f; stop1[threadIdx.x] = 0; }
  __syncthreads();

#pragma unroll
  for (int i = 0; i < 4; i++) {
    int s = wave * 4 + i;
    int t = blockIdx.x * 16 + s;
    float acc[8];
#pragma unroll
    for (int e = 0; e < 8; e++) acc[e] = 0.f;
    const float* xr = x + (size_t)t * DMODEL;
    for (int c = lane; c < DMODEL / 4; c += 64) {
      f32x4 xv = ((const f32x4*)xr)[c];
      const float* wr = Wg + (size_t)c * 4 * 8;
#pragma unroll
      for (int q = 0; q < 4; q++)
#pragma unroll
        for (int e = 0; e < 8; e++) acc[e] += xv[q] * wr[q * 8 + e];
    }
#pragma unroll
    for (int off = 32; off > 0; off >>= 1) {
#pragma unroll
      for (int e = 0; e < 8; e++) acc[e] += __shfl_down(acc[e], off);
    }
    if (lane == 0) {
      float p[8];
      float m = -1e30f;
#pragma unroll
      for (int e = 0; e < 8; e++) { p[e] = acc[e] + bg[e]; m = fmaxf(m, p[e]); }
      float sum = 0.f;
#pragma unroll
      for (int e = 0; e < 8; e++) { p[e] = __expf(p[e] - m); sum += p[e]; }
      float inv = 1.f / sum;
#pragma unroll
      for (int e = 0; e < 8; e++) p[e] *= inv;
      int e1 = 0; float p1 = p[0];
#pragma unroll
      for (int e = 1; e < 8; e++) if (p[e] > p1) { p1 = p[e]; e1 = e; }   // strict > : lowest idx wins ties
      int e2 = -1; float p2 = -1.f;
#pragma unroll
      for (int e = 0; e < 8; e++) if (e != e1 && p[e] > p2) { p2 = p[e]; e2 = e; }
      atomicAdd(&stop1[e1], 1);                     // LDS atomic
#pragma unroll
      for (int e = 0; e < 8; e++) atomicAdd(&sprob[e], p[e]);   // LDS atomics
      ent_e[2 * s]     = e1; ent_p[2 * s]     = p1;
      ent_e[2 * s + 1] = e2; ent_p[2 * s + 1] = p2;
    }
  }
  __syncthreads();

  if (threadIdx.x < 8) {
    int e = threadIdx.x;
    int n = 0;
#pragma unroll
    for (int j = 0; j < 32; j++) n += (ent_e[j] == e) ? 1 : 0;
    if (n) {
      int pos = atomicAdd(cnt + e, n);              // one ranged reservation per expert per block
#pragma unroll
      for (int j = 0; j < 32; j++) {
        if (ent_e[j] == e) {
          int t = blockIdx.x * 16 + (j >> 1);
          list[e * CAP + pos]  = t;
          wlist[e * CAP + pos] = ent_p[j];
          tok2slot[2 * t + (j & 1)] = (e << 16) | pos;   // pos < 2048 fits 16 bits
          pos++;
        }
      }
    }
    atomicAdd(sumprob + e, sprob[e]);               // one per expert per block
    int c = stop1[e];
    if (c) atomicAdd(top1cnt + e, c);
  }
}

// ---------------- offsets (prefix sum) + aux loss ----------------
__global__ void offs_aux_kernel(const int* cnt, const int* top1cnt, const float* sumprob,
                                int* offs, float* out_aux) {
  if (threadIdx.x == 0 && blockIdx.x == 0) {
    int off = 0;
    float aux = 0.f;
    for (int e = 0; e < 8; e++) {
      offs[e] = off; off += cnt[e];
      aux += ((float)top1cnt[e] / ((float)T_TOK + 1e-8f)) * (sumprob[e] / (float)T_TOK);
    }
    *out_aux = aux * (float)NEXP;
  }
}

// ---------------- gather x rows into compact bf16 buffer ----------------
__global__ void gather_kernel(const float* __restrict__ x, const int* __restrict__ list,
                              const int* __restrict__ cnt, const int* __restrict__ offs,
                              unsigned short* __restrict__ xg) {
  int e = blockIdx.x >> 11;
  int i = blockIdx.x & 2047;
  if (i >= cnt[e]) return;
  int t = list[e * CAP + i];
  int row = offs[e] + i;
  const f32x4* src = (const f32x4*)(x + (size_t)t * DMODEL);
  us4* dst = (us4*)(xg + (size_t)row * DMODEL);
  int j = threadIdx.x;                 // 256 threads x 4 elems = 1024
  f32x4 v = src[j];
  us4 o; o.x = f2bf(v.x); o.y = f2bf(v.y); o.z = f2bf(v.z); o.w = f2bf(v.w);
  dst[j] = o;
}

// ---- convert+transpose: fp32 in[E][Kfull][Nfull], k-slice [k_off,k_off+KS) and
// n-slice [n_off,n_off+NS) -> bf16 out[E][NS][KS] (row = n, contiguous = k) ----
__launch_bounds__(256)
__global__ void convt_kernel(const float* __restrict__ in, unsigned short* __restrict__ out,
                             int Kfull, int Nfull, int KS, int k_off, int NS, int n_off) {
  int e = blockIdx.y;
  int ntn = NS >> 6;
  int tk = blockIdx.x / ntn, tn = blockIdx.x % ntn;
  const float* src = in + (size_t)e * Kfull * Nfull + (size_t)(k_off + tk * 64) * Nfull + n_off + tn * 64;
  unsigned short* dst = out + (size_t)e * NS * KS + (size_t)(tn * 64) * KS + tk * 64;
  __shared__ unsigned short Ls[64 * 72];
  int t = threadIdx.x;
  int k = t >> 4, n4 = (t & 15) * 4;
#pragma unroll
  for (int i = 0; i < 4; i++) {
    int kk = k + 16 * i;
    f32x4 v = *(const f32x4*)&src[(size_t)kk * Nfull + n4];
    Ls[(n4 + 0) * 72 + kk] = f2bf(v.x);
    Ls[(n4 + 1) * 72 + kk] = f2bf(v.y);
    Ls[(n4 + 2) * 72 + kk] = f2bf(v.z);
    Ls[(n4 + 3) * 72 + kk] = f2bf(v.w);
  }
  __syncthreads();
  int n = t >> 3, k8 = (t & 7) * 8;
#pragma unroll
  for (int j = 0; j < 2; j++) {
    int nn = n + 32 * j;
    us8 v = *(const us8*)&Ls[nn * 72 + k8];
    *(us8*)&dst[(size_t)nn * KS + k8] = v;
  }
}

// ---------------- GEMM1 slice: h_s[:, 0:NS] = relu(xg @ W1[:, n_off:n_off+NS] + b1) ----
// Grid (e=8, nloc, mt): blockIdx.x = e => linear%8 = e => expert pinned to one XCD
// (per-expert A/B/y working set ~4MB fits that XCD's private L2 -> re-reads hit L2).
// LDS tiles are segment-major [kseg=4][128 rows][8 elems] so ds_read_b128 of a
// column of rows walks all 32 banks (was 8-way conflict at 64B row stride).
__launch_bounds__(256)
__global__ void gemm1_kernel(const unsigned short* __restrict__ xg,
                             const unsigned short* __restrict__ Wt,   // [E][NS][D] bf16
                             const float* __restrict__ b1,
                             const int* __restrict__ cnt, const int* __restrict__ offs,
                             unsigned short* __restrict__ h, int NS, int n_off) {
  int e = blockIdx.x;
  int mt = blockIdx.z;
  int count = cnt[e];
  if (mt * 128 >= count) return;
  int nloc = blockIdx.y * 128;
  int base = offs[e];
  const unsigned short* A = xg + (size_t)(base + mt * 128) * DMODEL;
  const unsigned short* B = Wt + (size_t)e * NS * DMODEL + (size_t)nloc * DMODEL;

  __shared__ unsigned short As[4 * 128 * 8];   // [kseg][row][8]
  __shared__ unsigned short Bs[4 * 128 * 8];

  int tid = threadIdx.x;
  int w = tid >> 6, lane = tid & 63;
  int wr = w >> 1, wc = w & 1;
  int l16 = lane & 15, quad = lane >> 4;

  f32x4 acc[4][4];
#pragma unroll
  for (int i = 0; i < 4; i++)
#pragma unroll
    for (int j = 0; j < 4; j++)
#pragma unroll
      for (int r = 0; r < 4; r++) acc[i][j][r] = 0.f;

  // wave w stages k-segment w (8 bf16 = 16B) for rows lane and 64+lane
  const unsigned short* Aw0 = A + (size_t)lane * DMODEL + w * 8;
  const unsigned short* Aw1 = A + (size_t)(64 + lane) * DMODEL + w * 8;
  const unsigned short* Bw0 = B + (size_t)lane * DMODEL + w * 8;
  const unsigned short* Bw1 = B + (size_t)(64 + lane) * DMODEL + w * 8;
  unsigned short* AsW0 = &As[w * 1024];
  unsigned short* AsW1 = &As[w * 1024 + 512];
  unsigned short* BsW0 = &Bs[w * 1024];
  unsigned short* BsW1 = &Bs[w * 1024 + 512];

  for (int kb = 0; kb < DMODEL / 32; kb++) {
    int ko = kb * 32;
    async16(Aw0 + ko, AsW0);
    async16(Aw1 + ko, AsW1);
    async16(Bw0 + ko, BsW0);
    async16(Bw1 + ko, BsW1);
    __syncthreads();
    short8 af[4], bf[4];
#pragma unroll
    for (int i = 0; i < 4; i++)
      af[i] = *(const short8*)&As[quad * 1024 + (wr * 64 + i * 16 + l16) * 8];
#pragma unroll
    for (int j = 0; j < 4; j++)
      bf[j] = *(const short8*)&Bs[quad * 1024 + (wc * 64 + j * 16 + l16) * 8];
#pragma unroll
    for (int i = 0; i < 4; i++)
#pragma unroll
      for (int j = 0; j < 4; j++)
        acc[i][j] = __builtin_amdgcn_mfma_f32_16x16x32_bf16(af[i], bf[j], acc[i][j], 0, 0, 0);
    __syncthreads();
  }

  // guard row<count: packed expert rows — unguarded writes clobber next expert
#pragma unroll
  for (int j = 0; j < 4; j++) {
    int ncl = nloc + wc * 64 + j * 16 + l16;           // local col within slice
    float bias = b1[e * FDIM + n_off + ncl];
#pragma unroll
    for (int i = 0; i < 4; i++) {
      int rbase = mt * 128 + wr * 64 + i * 16 + quad * 4;
#pragma unroll
      for (int r = 0; r < 4; r++) {
        int row = rbase + r;
        if (row < count) {
          float v = fmaxf(acc[i][j][r] + bias, 0.f);
          h[(size_t)(base + row) * NS + ncl] = f2bf(v);
        }
      }
    }
  }
}

// ---------------- GEMM2 slice: y[row, :] (+)= h_s @ W2[f_slice, :] (+ b2 on first slice) ----
// Dense per-routed-row output, plain stores / read-add-store. NO atomics.
// Same XCD-pinning + segment-major LDS as gemm1.
__launch_bounds__(256)
__global__ void gemm2_kernel(const unsigned short* __restrict__ h,
                             const unsigned short* __restrict__ Wt,   // [E][D][KS] bf16
                             const float* __restrict__ b2,
                             const int* __restrict__ cnt, const int* __restrict__ offs,
                             float* __restrict__ y, int KS, int first) {
  int e = blockIdx.x;
  int mt = blockIdx.z;
  int count = cnt[e];
  if (mt * 128 >= count) return;
  int nloc = blockIdx.y * 128;
  int base = offs[e];
  const unsigned short* A = h + (size_t)(base + mt * 128) * KS;
  const unsigned short* B = Wt + (size_t)e * DMODEL * KS + (size_t)nloc * KS;

  __shared__ unsigned short As[4 * 128 * 8];   // [kseg][row][8]
  __shared__ unsigned short Bs[4 * 128 * 8];

  int tid = threadIdx.x;
  int w = tid >> 6, lane = tid & 63;
  int wr = w >> 1, wc = w & 1;
  int l16 = lane & 15, quad = lane >> 4;

  f32x4 acc[4][4];
#pragma unroll
  for (int i = 0; i < 4; i++)
#pragma unroll
    for (int j = 0; j < 4; j++)
#pragma unroll
      for (int r = 0; r < 4; r++) acc[i][j][r] = 0.f;

  const unsigned short* Aw0 = A + (size_t)lane * KS + w * 8;
  const unsigned short* Aw1 = A + (size_t)(64 + lane) * KS + w * 8;
  const unsigned short* Bw0 = B + (size_t)lane * KS + w * 8;
  const unsigned short* Bw1 = B + (size_t)(64 + lane) * KS + w * 8;
  unsigned short* AsW0 = &As[w * 1024];
  unsigned short* AsW1 = &As[w * 1024 + 512];
  unsigned short* BsW0 = &Bs[w * 1024];
  unsigned short* BsW1 = &Bs[w * 1024 + 512];

  for (int kb = 0; kb < KS / 32; kb++) {
    int ko = kb * 32;
    async16(Aw0 + ko, AsW0);
    async16(Aw1 + ko, AsW1);
    async16(Bw0 + ko, BsW0);
    async16(Bw1 + ko, BsW1);
    __syncthreads();
    short8 af[4], bf[4];
#pragma unroll
    for (int i = 0; i < 4; i++)
      af[i] = *(const short8*)&As[quad * 1024 + (wr * 64 + i * 16 + l16) * 8];
#pragma unroll
    for (int j = 0; j < 4; j++)
      bf[j] = *(const short8*)&Bs[quad * 1024 + (wc * 64 + j * 16 + l16) * 8];
#pragma unroll
    for (int i = 0; i < 4; i++)
#pragma unroll
      for (int j = 0; j < 4; j++)
        acc[i][j] = __builtin_amdgcn_mfma_f32_16x16x32_bf16(af[i], bf[j], acc[i][j], 0, 0, 0);
    __syncthreads();
  }

  float bv[4];
#pragma unroll
  for (int j = 0; j < 4; j++)
    bv[j] = first ? b2[e * DMODEL + nloc + wc * 64 + j * 16 + l16] : 0.f;

#pragma unroll
  for (int i = 0; i < 4; i++) {
    int rbase = mt * 128 + wr * 64 + i * 16 + quad * 4;
#pragma unroll
    for (int r = 0; r < 4; r++) {
      int row = rbase + r;
      if (row >= count) continue;       // packed rows: unguarded writes clobber next expert
      float* yr = y + (size_t)(base + row) * DMODEL;
#pragma unroll
      for (int j = 0; j < 4; j++) {
        int ncol = nloc + wc * 64 + j * 16 + l16;
        float v = acc[i][j][r] + bv[j];
        if (first) yr[ncol] = v;
        else       yr[ncol] += v;
      }
    }
  }
}

// ---------------- combine: out[t,:] = w0*y[r0,:] + w1*y[r1,:] ----------------
__global__ void combine_kernel(const float* __restrict__ y, const int* __restrict__ offs,
                               const int* __restrict__ tok2slot, const float* __restrict__ wlist,
                               float* __restrict__ out) {
  int t = blockIdx.x;
  int s0 = tok2slot[2 * t], s1 = tok2slot[2 * t + 1];
  int e0 = s0 >> 16, p0 = s0 & 0xffff;
  int e1 = s1 >> 16, p1 = s1 & 0xffff;
  float w0 = wlist[e0 * CAP + p0], w1 = wlist[e1 * CAP + p1];
  int r0 = offs[e0] + p0, r1 = offs[e1] + p1;
  int j = threadIdx.x * 4;
  f32x4 a = *(const f32x4*)&y[(size_t)r0 * DMODEL + j];
  f32x4 b = *(const f32x4*)&y[(size_t)r1 * DMODEL + j];
  f32x4 o;
  o.x = w0 * a.x + w1 * b.x;
  o.y = w0 * a.y + w1 * b.y;
  o.z = w0 * a.z + w1 * b.z;
  o.w = w0 * a.w + w1 * b.w;
  *(f32x4*)&out[(size_t)t * DMODEL + j] = o;
}

extern "C" void kernel_launch(void* const* d_in, const int* in_sizes, int n_in,
                              void* d_out, int out_size, void* d_ws, size_t ws_size,
                              hipStream_t stream) {
  const float* x  = (const float*)d_in[0];
  const float* Wg = (const float*)d_in[1];
  const float* bg = (const float*)d_in[2];
  const float* W1 = (const float*)d_in[3];
  const float* b1 = (const float*)d_in[4];
  const float* W2 = (const float*)d_in[5];
  const float* b2 = (const float*)d_in[6];
  float* out = (float*)d_out;

  // Workspace layout (S=4 total: 50,483,200 B <= proven-safe 51.38 MB):
  //   small @0..128 | list 64K @4096 | wlist 64K @69632 | tok2slot 16K @135168
  //   xg 8M @151552 | h_s 32M/S | y 16M | Wt 64M/S
  char* ws = (char*)d_ws;
  int*   cnt      = (int*)(ws + 0);
  int*   top1cnt  = (int*)(ws + 32);
  int*   offs     = (int*)(ws + 64);
  float* sumprob  = (float*)(ws + 96);
  int*   list     = (int*)(ws + 4096);
  float* wlist    = (float*)(ws + 69632);
  int*   tok2slot = (int*)(ws + 135168);
  unsigned short* xg = (unsigned short*)(ws + 151552);        // 8,388,608 B -> 8,540,160

  // pick slice count S from ws_size (stable across calls -> same work every call)
  const size_t fixed = 8540160ull + 16777216ull;              // ..xg end + y
  int S = 8;
  if      (ws_size >= fixed + 100663296ull)     S = 1;
  else if (ws_size >= fixed + 100663296ull / 2) S = 2;
  else if (ws_size >= fixed + 100663296ull / 4) S = 4;        // 50.48 MB
  const int NS1 = FDIM / S;
  unsigned short* h  = (unsigned short*)(ws + 8540160);                        // 33,554,432/S
  float*          y  = (float*)(ws + 8540160 + 33554432ull / S);               // 16 MB
  unsigned short* Wt = (unsigned short*)(ws + 8540160 + 33554432ull / S + 16777216ull);

  hipMemsetAsync(ws, 0, 1024, stream);

  gate_kernel<<<T_TOK / 16, 256, 0, stream>>>(x, Wg, bg, cnt, top1cnt, sumprob, list, wlist, tok2slot);
  offs_aux_kernel<<<1, 64, 0, stream>>>(cnt, top1cnt, sumprob, offs, out + (size_t)T_TOK * DMODEL);
  gather_kernel<<<NEXP * CAP, 256, 0, stream>>>(x, list, cnt, offs, xg);

  for (int s = 0; s < S; s++) {
    // W1 slice: in [E][D][F], k=d full, n=f slice -> Wt [E][NS1][D]
    convt_kernel<<<dim3((DMODEL / 64) * (NS1 / 64), NEXP), 256, 0, stream>>>(
        W1, Wt, DMODEL, FDIM, DMODEL, 0, NS1, s * NS1);
    gemm1_kernel<<<dim3(NEXP, NS1 / 128, 16), 256, 0, stream>>>(
        xg, Wt, b1, cnt, offs, h, NS1, s * NS1);
    // W2 slice: in [E][F][D], k=f slice, n=d full -> Wt [E][D][NS1]
    convt_kernel<<<dim3((NS1 / 64) * (DMODEL / 64), NEXP), 256, 0, stream>>>(
        W2, Wt, FDIM, DMODEL, NS1, s * NS1, DMODEL, 0);
    gemm2_kernel<<<dim3(NEXP, DMODEL / 128, 16), 256, 0, stream>>>(
        h, Wt, b2, cnt, offs, y, NS1, s == 0 ? 1 : 0);
  }

  combine_kernel<<<T_TOK, 256, 0, stream>>>(y, offs, tok2slot, wlist, out);
}